// Round 5
// baseline (70.746 us; speedup 1.0000x reference)
//
#include <hip/hip_runtime.h>
#include <math.h>

typedef float f4     __attribute__((ext_vector_type(4)));
typedef float f32x4  __attribute__((ext_vector_type(4)));
typedef float f32x2  __attribute__((ext_vector_type(2)));
typedef short bf16x8 __attribute__((ext_vector_type(8)));
typedef unsigned short u16x4 __attribute__((ext_vector_type(4)));
typedef unsigned int   u32x4 __attribute__((ext_vector_type(4)));

// Problem constants: B=4096, L=5, K=32, N=16384, U=131072, V=500000, F=256, E=256
#define NROWS   16384
#define KNEI    32
#define FDIM    256
#define TWOF    512
#define EDIM    256
#define BATCH   4096
#define UROWS   131072
#define FP8_SCALE 512.0f   // table*512 in e4m3: max |v|~61 << 448, keeps normals
#define BM      32         // fused-kernel rows per block

static __device__ __forceinline__ unsigned short f2bf(float x) {
    union { float f; unsigned int i; } c; c.f = x;
    unsigned int u = c.i;
    u += 0x7fffu + ((u >> 16) & 1u);      // round-to-nearest-even
    return (unsigned short)(u >> 16);
}

// ===========================================================================
// FAST PATH
// ws layout: [0,32MiB)       embed_fp8[U][256]   (scaled x512)
//            [32MiB,+256KiB) W_bf16[256][512]
// ===========================================================================

#define EMBED_BLKS (UROWS / 4)              // 32768
#define CELL_BLKS  (BATCH / 4)              // 1024
#define WCONV_BLKS (EDIM * TWOF / 4 / 256)  // 128

// prep: embed fp8 conversion + cell copy + W bf16 conversion, by block range
__global__ __launch_bounds__(256) void prep_kernel(
    const int* __restrict__ unique_nodes, const float* __restrict__ table,
    const int* __restrict__ nodes, const float* __restrict__ W,
    unsigned int* __restrict__ embed, float* __restrict__ out,
    unsigned short* __restrict__ Wb)
{
    const int wave = threadIdx.x >> 6;
    const int lane = threadIdx.x & 63;
    const int blk  = blockIdx.x;

    if (blk < EMBED_BLKS) {
        const int u   = blk * 4 + wave;
        const int row = unique_nodes[u];
        const f4 e = *(const f4*)(table + (size_t)row * FDIM + lane * 4);
        int r = 0;
        r = __builtin_amdgcn_cvt_pk_fp8_f32(e[0] * FP8_SCALE, e[1] * FP8_SCALE, r, 0);
        r = __builtin_amdgcn_cvt_pk_fp8_f32(e[2] * FP8_SCALE, e[3] * FP8_SCALE, r, 1);
        embed[((size_t)u << 6) + lane] = (unsigned int)r;   // 64 dwords per row
    } else if (blk < EMBED_BLKS + CELL_BLKS) {
        const int b = (blk - EMBED_BLKS) * 4 + wave;
        const int node = nodes[b * 5];
        const f4 e = *(const f4*)(table + (size_t)node * FDIM + lane * 4);
        *(f4*)(out + (size_t)b * 5 * FDIM + lane * 4) = e;
    } else {
        const int t = (blk - EMBED_BLKS - CELL_BLKS) * 256 + threadIdx.x;
        const f4 w = *(const f4*)(W + (size_t)t * 4);
        u16x4 o;
        #pragma unroll
        for (int j = 0; j < 4; ++j) o[j] = f2bf(w[j]);
        *(u16x4*)(Wb + (size_t)t * 4) = o;
    }
}

// Fused gather + GEMM + SiLU. Block = 512 threads (8 waves), owns BM=32 rows.
// Phase 1 (quarter-wave per row): wave owns 4 rows; lane l handles row
//   (l>>4), fp8 cols (l&15)*16..+16 (16B per gather load). 32 k-iterations.
//   Results -> XOR-swizzled LDS A-tile (bf16, 32 KB).
// Phase 2: mfma_f32_16x16x32_bf16; A-frags ds_read_b128 from LDS (swizzled,
//   conflict-free), B-frags direct from L2-resident Wb. Wave-tile 32x32.
// Swizzle: byte(r,2k) = r*1024 + ((2k) ^ ((r&7)<<4)); all accesses 16B-aligned.
__global__ __launch_bounds__(512, 4) void fused_kernel(
    const int* __restrict__ mask_col, const float* __restrict__ mask_val,
    const unsigned int* __restrict__ embed, const int* __restrict__ nodes,
    const float* __restrict__ table, const unsigned short* __restrict__ Wb,
    const float* __restrict__ bias, float* __restrict__ out)
{
    __shared__ unsigned short As[BM * TWOF];   // 32 KB, swizzled
    char* const As_b = (char*)As;

    const int wave  = threadIdx.x >> 6;
    const int lane  = threadIdx.x & 63;
    const int q     = lane >> 4;        // 0..3 : which of the wave's 4 rows
    const int l16   = lane & 15;        // position within quarter-wave
    const int rbase = blockIdx.x * BM;

    // ---------------- Phase 1: gather (4 rows per wave, concurrently) ------
    const int lr = wave * 4 + q;        // local row 0..31
    const int gi = rbase + lr;          // global row

    // mask entries: lane l holds k=(l16) and k=16+l16 for row gi
    const int j0 = gi * KNEI + l16;
    const int col0 = mask_col[j0];
    const int col1 = mask_col[j0 + 16];
    const float val0 = mask_val[j0]      * (1.0f / FP8_SCALE);
    const float val1 = mask_val[j0 + 16] * (1.0f / FP8_SCALE);

    // self row (issue early; independent of gather loop)
    const int nfr = nodes[(gi >> 2) * 5 + 1 + (gi & 3)];
    const float* sp = table + (size_t)nfr * FDIM + l16 * 16;
    const f4 s0 = *(const f4*)sp;
    const f4 s1 = *(const f4*)(sp + 4);
    const f4 s2 = *(const f4*)(sp + 8);
    const f4 s3 = *(const f4*)(sp + 12);

    // acc: this lane's 16 f32 columns of its row's neigh half
    f4 a0 = (f4){0.f,0.f,0.f,0.f}, a1 = a0, a2 = a0, a3 = a0;

    #pragma unroll 8
    for (int k = 0; k < KNEI; ++k) {
        const int src = (lane & 48) | (k & 15);
        const int   c = __shfl(k < 16 ? col0 : col1, src);
        const float v = __shfl(k < 16 ? val0 : val1, src);
        // 16 fp8 = 4 dwords; lane covers dwords l16*4..+4 of row c
        const u32x4 w = *(const u32x4*)(embed + ((size_t)c << 6) + l16 * 4);
        #pragma unroll
        for (int d = 0; d < 4; ++d) {
            const f32x2 lo = __builtin_amdgcn_cvt_pk_f32_fp8((int)w[d], 0);
            const f32x2 hi = __builtin_amdgcn_cvt_pk_f32_fp8((int)w[d], 1);
            f4* acc = (d == 0) ? &a0 : (d == 1) ? &a1 : (d == 2) ? &a2 : &a3;
            (*acc)[0] += v * lo[0]; (*acc)[1] += v * lo[1];
            (*acc)[2] += v * hi[0]; (*acc)[3] += v * hi[1];
        }
    }

    const int swz = (lr & 7) << 4;

    // neigh half: cols l16*16..+16 -> bytes l16*32 (^swz), two b128 stores
    u32x4 on0, on1;
    on0[0] = (unsigned)f2bf(a0[0]) | ((unsigned)f2bf(a0[1]) << 16);
    on0[1] = (unsigned)f2bf(a0[2]) | ((unsigned)f2bf(a0[3]) << 16);
    on0[2] = (unsigned)f2bf(a1[0]) | ((unsigned)f2bf(a1[1]) << 16);
    on0[3] = (unsigned)f2bf(a1[2]) | ((unsigned)f2bf(a1[3]) << 16);
    on1[0] = (unsigned)f2bf(a2[0]) | ((unsigned)f2bf(a2[1]) << 16);
    on1[1] = (unsigned)f2bf(a2[2]) | ((unsigned)f2bf(a2[3]) << 16);
    on1[2] = (unsigned)f2bf(a3[0]) | ((unsigned)f2bf(a3[1]) << 16);
    on1[3] = (unsigned)f2bf(a3[2]) | ((unsigned)f2bf(a3[3]) << 16);
    *(u32x4*)(As_b + lr * 1024 + (((l16 * 32)     ) ^ swz)) = on0;
    *(u32x4*)(As_b + lr * 1024 + (((l16 * 32) + 16) ^ swz)) = on1;

    // self half: cols 256+l16*16..+16 -> bytes 512+l16*32 (^swz)
    u32x4 os0, os1;
    os0[0] = (unsigned)f2bf(s0[0]) | ((unsigned)f2bf(s0[1]) << 16);
    os0[1] = (unsigned)f2bf(s0[2]) | ((unsigned)f2bf(s0[3]) << 16);
    os0[2] = (unsigned)f2bf(s1[0]) | ((unsigned)f2bf(s1[1]) << 16);
    os0[3] = (unsigned)f2bf(s1[2]) | ((unsigned)f2bf(s1[3]) << 16);
    os1[0] = (unsigned)f2bf(s2[0]) | ((unsigned)f2bf(s2[1]) << 16);
    os1[1] = (unsigned)f2bf(s2[2]) | ((unsigned)f2bf(s2[3]) << 16);
    os1[2] = (unsigned)f2bf(s3[0]) | ((unsigned)f2bf(s3[1]) << 16);
    os1[3] = (unsigned)f2bf(s3[2]) | ((unsigned)f2bf(s3[3]) << 16);
    *(u32x4*)(As_b + lr * 1024 + ((512 + l16 * 32     ) ^ swz)) = os0;
    *(u32x4*)(As_b + lr * 1024 + ((512 + l16 * 32 + 16) ^ swz)) = os1;

    __syncthreads();

    // ---------------- Phase 2: MFMA (wave-tile 32 x 32) --------------------
    const int n_w    = wave * 32;              // this wave's 32 output cols
    const int lrow16 = lane & 15;
    const int koff   = (lane >> 4) * 8;
    const int aswz   = (lrow16 & 7) << 4;

    f32x4 acc[2][2] = {};
    const unsigned short* wp = Wb + (size_t)(n_w + lrow16) * TWOF + koff;

    #pragma unroll 4
    for (int kb = 0; kb < TWOF; kb += 32) {
        const int kbyte = (koff + kb) * 2;
        const bf16x8 fa0 = *(const bf16x8*)(As_b + (lrow16     ) * 1024 + (kbyte ^ aswz));
        const bf16x8 fa1 = *(const bf16x8*)(As_b + (lrow16 + 16) * 1024 + (kbyte ^ aswz));
        const bf16x8 fb0 = *(const bf16x8*)(wp + kb);
        const bf16x8 fb1 = *(const bf16x8*)(wp + 16 * TWOF + kb);
        acc[0][0] = __builtin_amdgcn_mfma_f32_16x16x32_bf16(fa0, fb0, acc[0][0], 0, 0, 0);
        acc[0][1] = __builtin_amdgcn_mfma_f32_16x16x32_bf16(fa0, fb1, acc[0][1], 0, 0, 0);
        acc[1][0] = __builtin_amdgcn_mfma_f32_16x16x32_bf16(fa1, fb0, acc[1][0], 0, 0, 0);
        acc[1][1] = __builtin_amdgcn_mfma_f32_16x16x32_bf16(fa1, fb1, acc[1][1], 0, 0, 0);
    }

    float bn[2];
    #pragma unroll
    for (int ni = 0; ni < 2; ++ni) bn[ni] = bias[n_w + ni * 16 + lrow16];

    // C/D layout: col = lane&15, row = (lane>>4)*4 + j   [verified rounds 2-4]
    #pragma unroll
    for (int mi = 0; mi < 2; ++mi) {
        #pragma unroll
        for (int ni = 0; ni < 2; ++ni) {
            const int n = n_w + ni * 16 + lrow16;
            #pragma unroll
            for (int j = 0; j < 4; ++j) {
                const int i = rbase + mi * 16 + (lane >> 4) * 4 + j;
                float h = acc[mi][ni][j] + bn[ni];
                h = h / (1.0f + __expf(-h));
                out[((size_t)(i >> 2) * 5 + 1 + (i & 3)) * FDIM + n] = h;
            }
        }
    }
}

// ===========================================================================
// FALLBACK PATH (all-f32) — used only if ws_size is too small
// ===========================================================================
__global__ __launch_bounds__(256) void neigh_f32_kernel(
    const int* __restrict__ mask_col, const float* __restrict__ mask_val,
    const int* __restrict__ unique_nodes, const float* __restrict__ table,
    float* __restrict__ neigh)
{
    const int wave = threadIdx.x >> 6;
    const int lane = threadIdx.x & 63;
    const int i = blockIdx.x * 4 + wave;
    int   row_l = 0;
    float val_l = 0.0f;
    if (lane < KNEI) {
        const int j = i * KNEI + lane;
        const int c = mask_col[j];
        val_l = mask_val[j];
        row_l = unique_nodes[c];
    }
    f4 acc = (f4){0.f, 0.f, 0.f, 0.f};
    #pragma unroll 8
    for (int k = 0; k < KNEI; ++k) {
        const int   row = __shfl(row_l, k);
        const float v   = __shfl(val_l, k);
        const f4 e = *(const f4*)(table + (size_t)row * FDIM + lane * 4);
        acc += v * e;
    }
    *(f4*)(neigh + (size_t)i * FDIM + lane * 4) = acc;
}

__global__ __launch_bounds__(256) void cell_kernel(
    const int* __restrict__ nodes, const float* __restrict__ table,
    float* __restrict__ out)
{
    const int wave = threadIdx.x >> 6;
    const int lane = threadIdx.x & 63;
    const int b = blockIdx.x * 4 + wave;
    const int node = nodes[b * 5];
    const f4 e = *(const f4*)(table + (size_t)node * FDIM + lane * 4);
    *(f4*)(out + (size_t)b * 5 * FDIM + lane * 4) = e;
}

__global__ __launch_bounds__(256) void gemm_f32_kernel(
    const float* __restrict__ neigh, const float* __restrict__ table,
    const int* __restrict__ nodes, const float* __restrict__ W,
    const float* __restrict__ bias, float* __restrict__ out)
{
    __shared__ float Asf[16][64];
    __shared__ float Wsf[16][64];
    const int t  = threadIdx.x;
    const int i0 = blockIdx.x * 64;
    const int e0 = blockIdx.y * 64;
    const int r  = t >> 2;
    const int k4 = (t & 3) << 2;
    const int irow = i0 + r;
    const int nfr = nodes[(irow >> 2) * 5 + 1 + (irow & 3)];
    const int tm = (t >> 4) << 2;
    const int tn = (t & 15) << 2;
    float acc[4][4] = {};
    for (int kb = 0; kb < TWOF; kb += 16) {
        const float* asrc = (kb < FDIM)
            ? (neigh + (size_t)irow * FDIM + kb + k4)
            : (table + (size_t)nfr  * FDIM + (kb - FDIM) + k4);
        const f4 av = *(const f4*)asrc;
        const f4 wv = *(const f4*)(W + (size_t)(e0 + r) * TWOF + kb + k4);
        __syncthreads();
        #pragma unroll
        for (int j = 0; j < 4; ++j) { Asf[k4 + j][r] = av[j]; Wsf[k4 + j][r] = wv[j]; }
        __syncthreads();
        #pragma unroll
        for (int k = 0; k < 16; ++k) {
            const f4 a = *(const f4*)&Asf[k][tm];
            const f4 w = *(const f4*)&Wsf[k][tn];
            #pragma unroll
            for (int mi = 0; mi < 4; ++mi)
                #pragma unroll
                for (int ni = 0; ni < 4; ++ni)
                    acc[mi][ni] += a[mi] * w[ni];
        }
    }
    #pragma unroll
    for (int mi = 0; mi < 4; ++mi) {
        const int i  = i0 + tm + mi;
        float* op = out + ((size_t)(i >> 2) * 5 + 1 + (i & 3)) * FDIM + e0 + tn;
        f4 hv;
        #pragma unroll
        for (int ni = 0; ni < 4; ++ni) {
            const float h = acc[mi][ni] + bias[e0 + tn + ni];
            hv[ni] = h / (1.0f + __expf(-h));
        }
        *(f4*)op = hv;
    }
}

// ===========================================================================
extern "C" void kernel_launch(void* const* d_in, const int* in_sizes, int n_in,
                              void* d_out, int out_size, void* d_ws, size_t ws_size,
                              hipStream_t stream)
{
    const int*   nodes        = (const int*)  d_in[0];
    const int*   mask_col     = (const int*)  d_in[2];
    const float* mask_val     = (const float*)d_in[3];
    const int*   unique_nodes = (const int*)  d_in[4];
    const float* table        = (const float*)d_in[5];
    const float* W            = (const float*)d_in[6];
    const float* bias         = (const float*)d_in[7];
    float*       out          = (float*)d_out;

    const size_t EMBED_B = (size_t)UROWS * FDIM;              // 32 MiB (fp8)
    const size_t W_B     = (size_t)EDIM  * TWOF * 2;          // 256 KiB

    if (ws_size >= EMBED_B + W_B) {
        unsigned int*   embed = (unsigned int*)d_ws;
        unsigned short* Wb    = (unsigned short*)((char*)d_ws + EMBED_B);

        prep_kernel<<<EMBED_BLKS + CELL_BLKS + WCONV_BLKS, 256, 0, stream>>>(
            unique_nodes, table, nodes, W, embed, out, Wb);
        fused_kernel<<<NROWS / BM, 512, 0, stream>>>(
            mask_col, mask_val, embed, nodes, table, Wb, bias, out);
    } else {
        float* neigh = (float*)d_ws;   // 16 MB
        neigh_f32_kernel<<<NROWS / 4, 256, 0, stream>>>(mask_col, mask_val,
                                                        unique_nodes, table, neigh);
        cell_kernel     <<<BATCH / 4, 256, 0, stream>>>(nodes, table, out);
        gemm_f32_kernel <<<dim3(NROWS / 64, EDIM / 64), 256, 0, stream>>>(
            neigh, table, nodes, W, bias, out);
    }
}

// Round 6
// 70.254 us; speedup vs baseline: 1.0070x; 1.0070x over previous
//
#include <hip/hip_runtime.h>
#include <math.h>

typedef float f4     __attribute__((ext_vector_type(4)));
typedef float f32x4  __attribute__((ext_vector_type(4)));
typedef float f32x2  __attribute__((ext_vector_type(2)));
typedef short bf16x8 __attribute__((ext_vector_type(8)));
typedef unsigned short u16x4 __attribute__((ext_vector_type(4)));
typedef unsigned int   u32x4 __attribute__((ext_vector_type(4)));
typedef unsigned int   u32x2 __attribute__((ext_vector_type(2)));

// Problem constants: B=4096, L=5, K=32, N=16384, U=131072, V=500000, F=256, E=256
#define NROWS   16384
#define KNEI    32
#define FDIM    256
#define TWOF    512
#define EDIM    256
#define BATCH   4096
#define UROWS   131072
#define FP8_SCALE 512.0f   // table*512 in e4m3: max |v|~61 << 448, keeps normals
#define BM      32         // fused-kernel rows per block

static __device__ __forceinline__ unsigned short f2bf(float x) {
    union { float f; unsigned int i; } c; c.f = x;
    unsigned int u = c.i;
    u += 0x7fffu + ((u >> 16) & 1u);      // round-to-nearest-even
    return (unsigned short)(u >> 16);
}

// ===========================================================================
// FAST PATH
// ws layout: [0,32MiB)       embed_fp8[U][256]   (scaled x512)
//            [32MiB,+256KiB) W_bf16[256][512]
// ===========================================================================

// Persistent prep: fat blocks, 16 rows per wave, software-pipelined by the
// compiler (independent iterations -> deep MLP instead of 1 load/block).
#define EMBED_PB   2048                     // blocks for embed section
#define CELL_PB    64                       // blocks for cell section
#define WCONV_PB   8                        // blocks for wconv section
#define ROWS_PW    16                       // rows per wave (embed/cell)

__global__ __launch_bounds__(256) void prep_kernel(
    const int* __restrict__ unique_nodes, const float* __restrict__ table,
    const int* __restrict__ nodes, const float* __restrict__ W,
    unsigned int* __restrict__ embed, float* __restrict__ out,
    unsigned short* __restrict__ Wb)
{
    const int wave = threadIdx.x >> 6;
    const int lane = threadIdx.x & 63;
    const int blk  = blockIdx.x;

    if (blk < EMBED_PB) {
        // embed_fp8[u][:] = e4m3(table[unique_nodes[u]][:] * 512)
        const int u0 = (blk * 4 + wave) * ROWS_PW;
        #pragma unroll 4
        for (int t = 0; t < ROWS_PW; ++t) {
            const int u   = u0 + t;
            const int row = unique_nodes[u];
            const f4 e = *(const f4*)(table + (size_t)row * FDIM + lane * 4);
            int r = 0;
            r = __builtin_amdgcn_cvt_pk_fp8_f32(e[0] * FP8_SCALE, e[1] * FP8_SCALE, r, 0);
            r = __builtin_amdgcn_cvt_pk_fp8_f32(e[2] * FP8_SCALE, e[3] * FP8_SCALE, r, 1);
            embed[((size_t)u << 6) + lane] = (unsigned int)r;
        }
    } else if (blk < EMBED_PB + CELL_PB) {
        // out[b][0][:] = table[nodes[b][0]][:]  (exact f32 copy)
        const int b0 = ((blk - EMBED_PB) * 4 + wave) * ROWS_PW;
        #pragma unroll 4
        for (int t = 0; t < ROWS_PW; ++t) {
            const int b = b0 + t;
            const int node = nodes[b * 5];
            const f4 e = *(const f4*)(table + (size_t)node * FDIM + lane * 4);
            *(f4*)(out + (size_t)b * 5 * FDIM + lane * 4) = e;
        }
    } else {
        // Wb = bf16(W): 32768 f4-quads over 8 blocks x 256 threads x 16 iters
        const int base = (blk - EMBED_PB - CELL_PB) * 256 * 16 + threadIdx.x;
        #pragma unroll 4
        for (int t = 0; t < 16; ++t) {
            const int idx = base + t * 256;
            const f4 w = *(const f4*)(W + (size_t)idx * 4);
            u16x4 o;
            #pragma unroll
            for (int j = 0; j < 4; ++j) o[j] = f2bf(w[j]);
            *(u16x4*)(Wb + (size_t)idx * 4) = o;
        }
    }
}

// Fused gather + GEMM + SiLU (round-4 pairwise structure, banked best).
// Block = 512 threads (8 waves), owns BM=32 rows.
// Phase 1: gather [neigh|self] into XOR-swizzled LDS A-tile (bf16, 32 KB).
//   Pair-wise: half-wave per row, 8 fp8 (8B) per lane per k-iter.
// Phase 2: mfma_f32_16x16x32_bf16; A-frags ds_read_b128 from LDS (swizzled,
//   conflict-free), B-frags direct from L2-resident Wb. Wave-tile 32x32.
// Swizzle: byte(r,2k) = r*1024 + ((2k) ^ ((r&7)<<4)); all accesses 16B-aligned.
__global__ __launch_bounds__(512, 4) void fused_kernel(
    const int* __restrict__ mask_col, const float* __restrict__ mask_val,
    const unsigned int* __restrict__ embed, const int* __restrict__ nodes,
    const float* __restrict__ table, const unsigned short* __restrict__ Wb,
    const float* __restrict__ bias, float* __restrict__ out)
{
    __shared__ unsigned short As[BM * TWOF];   // 32 KB, swizzled
    char* const As_b = (char*)As;

    const int wave  = threadIdx.x >> 6;
    const int lane  = threadIdx.x & 63;
    const int half  = lane >> 5;       // 0/1: which row of the pair
    const int l32   = lane & 31;
    const int rbase = blockIdx.x * BM;

    // ---------------- Phase 1: gather (2 pairs = 4 rows per wave) ----------
    #pragma unroll
    for (int p = 0; p < 2; ++p) {
        const int lr = wave * 4 + p * 2;       // local row (pair base)
        const int gi = rbase + lr;             // global row (pair base)

        // lanes 0..31 -> row gi's 32 entries; lanes 32..63 -> row gi+1's
        const int j   = gi * KNEI + lane;
        const int col = mask_col[j];
        const float val = mask_val[j] * (1.0f / FP8_SCALE);

        // self row for this half-wave (independent: issue early)
        const int i_g = gi + half;
        const int nfr = nodes[(i_g >> 2) * 5 + 1 + (i_g & 3)];
        const float* sp = table + (size_t)nfr * FDIM + l32 * 8;
        const f4 s0 = *(const f4*)sp;
        const f4 s1 = *(const f4*)(sp + 4);

        f4 accA = (f4){0.f,0.f,0.f,0.f};
        f4 accB = (f4){0.f,0.f,0.f,0.f};
        #pragma unroll 8
        for (int k = 0; k < KNEI; ++k) {
            const int   c = __shfl(col, (lane & 32) + k);
            const float v = __shfl(val, (lane & 32) + k);
            const u32x2 w = *(const u32x2*)(embed + ((size_t)c << 6) + l32 * 2);
            const f32x2 d0 = __builtin_amdgcn_cvt_pk_f32_fp8((int)w[0], 0);
            const f32x2 d1 = __builtin_amdgcn_cvt_pk_f32_fp8((int)w[0], 1);
            const f32x2 d2 = __builtin_amdgcn_cvt_pk_f32_fp8((int)w[1], 0);
            const f32x2 d3 = __builtin_amdgcn_cvt_pk_f32_fp8((int)w[1], 1);
            accA[0] += v * d0[0]; accA[1] += v * d0[1];
            accA[2] += v * d1[0]; accA[3] += v * d1[1];
            accB[0] += v * d2[0]; accB[1] += v * d2[1];
            accB[2] += v * d3[0]; accB[3] += v * d3[1];
        }

        const int lrow = lr + half;
        const int swz  = (lrow & 7) << 4;

        // neigh half: cols 8*l32..+8 -> bytes l32*16 (^swz)
        u32x4 on;
        on[0] = (unsigned)f2bf(accA[0]) | ((unsigned)f2bf(accA[1]) << 16);
        on[1] = (unsigned)f2bf(accA[2]) | ((unsigned)f2bf(accA[3]) << 16);
        on[2] = (unsigned)f2bf(accB[0]) | ((unsigned)f2bf(accB[1]) << 16);
        on[3] = (unsigned)f2bf(accB[2]) | ((unsigned)f2bf(accB[3]) << 16);
        *(u32x4*)(As_b + lrow * 1024 + ((l32 * 16) ^ swz)) = on;

        // self half: cols 256+8*l32 -> bytes 512+l32*16 (^swz)
        u32x4 os;
        os[0] = (unsigned)f2bf(s0[0]) | ((unsigned)f2bf(s0[1]) << 16);
        os[1] = (unsigned)f2bf(s0[2]) | ((unsigned)f2bf(s0[3]) << 16);
        os[2] = (unsigned)f2bf(s1[0]) | ((unsigned)f2bf(s1[1]) << 16);
        os[3] = (unsigned)f2bf(s1[2]) | ((unsigned)f2bf(s1[3]) << 16);
        *(u32x4*)(As_b + lrow * 1024 + ((512 + l32 * 16) ^ swz)) = os;
    }

    __syncthreads();

    // ---------------- Phase 2: MFMA (wave-tile 32 x 32) --------------------
    const int n_w    = wave * 32;              // this wave's 32 output cols
    const int lrow16 = lane & 15;
    const int koff   = (lane >> 4) * 8;
    const int aswz   = (lrow16 & 7) << 4;

    f32x4 acc[2][2] = {};
    const unsigned short* wp = Wb + (size_t)(n_w + lrow16) * TWOF + koff;

    #pragma unroll 4
    for (int kb = 0; kb < TWOF; kb += 32) {
        const int kbyte = (koff + kb) * 2;
        const bf16x8 a0 = *(const bf16x8*)(As_b + (lrow16     ) * 1024 + (kbyte ^ aswz));
        const bf16x8 a1 = *(const bf16x8*)(As_b + (lrow16 + 16) * 1024 + (kbyte ^ aswz));
        const bf16x8 b0 = *(const bf16x8*)(wp + kb);
        const bf16x8 b1 = *(const bf16x8*)(wp + 16 * TWOF + kb);
        acc[0][0] = __builtin_amdgcn_mfma_f32_16x16x32_bf16(a0, b0, acc[0][0], 0, 0, 0);
        acc[0][1] = __builtin_amdgcn_mfma_f32_16x16x32_bf16(a0, b1, acc[0][1], 0, 0, 0);
        acc[1][0] = __builtin_amdgcn_mfma_f32_16x16x32_bf16(a1, b0, acc[1][0], 0, 0, 0);
        acc[1][1] = __builtin_amdgcn_mfma_f32_16x16x32_bf16(a1, b1, acc[1][1], 0, 0, 0);
    }

    float bn[2];
    #pragma unroll
    for (int ni = 0; ni < 2; ++ni) bn[ni] = bias[n_w + ni * 16 + lrow16];

    // C/D layout: col = lane&15, row = (lane>>4)*4 + j   [verified rounds 2-5]
    #pragma unroll
    for (int mi = 0; mi < 2; ++mi) {
        #pragma unroll
        for (int ni = 0; ni < 2; ++ni) {
            const int n = n_w + ni * 16 + lrow16;
            #pragma unroll
            for (int j = 0; j < 4; ++j) {
                const int i = rbase + mi * 16 + (lane >> 4) * 4 + j;
                float h = acc[mi][ni][j] + bn[ni];
                h = h / (1.0f + __expf(-h));
                out[((size_t)(i >> 2) * 5 + 1 + (i & 3)) * FDIM + n] = h;
            }
        }
    }
}

// ===========================================================================
// FALLBACK PATH (all-f32) — used only if ws_size is too small
// ===========================================================================
__global__ __launch_bounds__(256) void neigh_f32_kernel(
    const int* __restrict__ mask_col, const float* __restrict__ mask_val,
    const int* __restrict__ unique_nodes, const float* __restrict__ table,
    float* __restrict__ neigh)
{
    const int wave = threadIdx.x >> 6;
    const int lane = threadIdx.x & 63;
    const int i = blockIdx.x * 4 + wave;
    int   row_l = 0;
    float val_l = 0.0f;
    if (lane < KNEI) {
        const int j = i * KNEI + lane;
        const int c = mask_col[j];
        val_l = mask_val[j];
        row_l = unique_nodes[c];
    }
    f4 acc = (f4){0.f, 0.f, 0.f, 0.f};
    #pragma unroll 8
    for (int k = 0; k < KNEI; ++k) {
        const int   row = __shfl(row_l, k);
        const float v   = __shfl(val_l, k);
        const f4 e = *(const f4*)(table + (size_t)row * FDIM + lane * 4);
        acc += v * e;
    }
    *(f4*)(neigh + (size_t)i * FDIM + lane * 4) = acc;
}

__global__ __launch_bounds__(256) void cell_kernel(
    const int* __restrict__ nodes, const float* __restrict__ table,
    float* __restrict__ out)
{
    const int wave = threadIdx.x >> 6;
    const int lane = threadIdx.x & 63;
    const int b = blockIdx.x * 4 + wave;
    const int node = nodes[b * 5];
    const f4 e = *(const f4*)(table + (size_t)node * FDIM + lane * 4);
    *(f4*)(out + (size_t)b * 5 * FDIM + lane * 4) = e;
}

__global__ __launch_bounds__(256) void gemm_f32_kernel(
    const float* __restrict__ neigh, const float* __restrict__ table,
    const int* __restrict__ nodes, const float* __restrict__ W,
    const float* __restrict__ bias, float* __restrict__ out)
{
    __shared__ float Asf[16][64];
    __shared__ float Wsf[16][64];
    const int t  = threadIdx.x;
    const int i0 = blockIdx.x * 64;
    const int e0 = blockIdx.y * 64;
    const int r  = t >> 2;
    const int k4 = (t & 3) << 2;
    const int irow = i0 + r;
    const int nfr = nodes[(irow >> 2) * 5 + 1 + (irow & 3)];
    const int tm = (t >> 4) << 2;
    const int tn = (t & 15) << 2;
    float acc[4][4] = {};
    for (int kb = 0; kb < TWOF; kb += 16) {
        const float* asrc = (kb < FDIM)
            ? (neigh + (size_t)irow * FDIM + kb + k4)
            : (table + (size_t)nfr  * FDIM + (kb - FDIM) + k4);
        const f4 av = *(const f4*)asrc;
        const f4 wv = *(const f4*)(W + (size_t)(e0 + r) * TWOF + kb + k4);
        __syncthreads();
        #pragma unroll
        for (int j = 0; j < 4; ++j) { Asf[k4 + j][r] = av[j]; Wsf[k4 + j][r] = wv[j]; }
        __syncthreads();
        #pragma unroll
        for (int k = 0; k < 16; ++k) {
            const f4 a = *(const f4*)&Asf[k][tm];
            const f4 w = *(const f4*)&Wsf[k][tn];
            #pragma unroll
            for (int mi = 0; mi < 4; ++mi)
                #pragma unroll
                for (int ni = 0; ni < 4; ++ni)
                    acc[mi][ni] += a[mi] * w[ni];
        }
    }
    #pragma unroll
    for (int mi = 0; mi < 4; ++mi) {
        const int i  = i0 + tm + mi;
        float* op = out + ((size_t)(i >> 2) * 5 + 1 + (i & 3)) * FDIM + e0 + tn;
        f4 hv;
        #pragma unroll
        for (int ni = 0; ni < 4; ++ni) {
            const float h = acc[mi][ni] + bias[e0 + tn + ni];
            hv[ni] = h / (1.0f + __expf(-h));
        }
        *(f4*)op = hv;
    }
}

// ===========================================================================
extern "C" void kernel_launch(void* const* d_in, const int* in_sizes, int n_in,
                              void* d_out, int out_size, void* d_ws, size_t ws_size,
                              hipStream_t stream)
{
    const int*   nodes        = (const int*)  d_in[0];
    const int*   mask_col     = (const int*)  d_in[2];
    const float* mask_val     = (const float*)d_in[3];
    const int*   unique_nodes = (const int*)  d_in[4];
    const float* table        = (const float*)d_in[5];
    const float* W            = (const float*)d_in[6];
    const float* bias         = (const float*)d_in[7];
    float*       out          = (float*)d_out;

    const size_t EMBED_B = (size_t)UROWS * FDIM;              // 32 MiB (fp8)
    const size_t W_B     = (size_t)EDIM  * TWOF * 2;          // 256 KiB

    if (ws_size >= EMBED_B + W_B) {
        unsigned int*   embed = (unsigned int*)d_ws;
        unsigned short* Wb    = (unsigned short*)((char*)d_ws + EMBED_B);

        prep_kernel<<<EMBED_PB + CELL_PB + WCONV_PB, 256, 0, stream>>>(
            unique_nodes, table, nodes, W, embed, out, Wb);
        fused_kernel<<<NROWS / BM, 512, 0, stream>>>(
            mask_col, mask_val, embed, nodes, table, Wb, bias, out);
    } else {
        float* neigh = (float*)d_ws;   // 16 MB
        neigh_f32_kernel<<<NROWS / 4, 256, 0, stream>>>(mask_col, mask_val,
                                                        unique_nodes, table, neigh);
        cell_kernel     <<<BATCH / 4, 256, 0, stream>>>(nodes, table, out);
        gemm_f32_kernel <<<dim3(NROWS / 64, EDIM / 64), 256, 0, stream>>>(
            neigh, table, nodes, W, bias, out);
    }
}

// Round 7
// 60.654 us; speedup vs baseline: 1.1664x; 1.1583x over previous
//
#include <hip/hip_runtime.h>
#include <math.h>

typedef float f4     __attribute__((ext_vector_type(4)));
typedef float f32x4  __attribute__((ext_vector_type(4)));
typedef short bf16x8 __attribute__((ext_vector_type(8)));
typedef unsigned short u16x4 __attribute__((ext_vector_type(4)));
typedef unsigned int   u32x4 __attribute__((ext_vector_type(4)));

// Problem constants: B=4096, L=5, K=32, N=16384, U=131072, V=500000, F=256, E=256
#define NROWS   16384
#define KNEI    32
#define FDIM    256
#define TWOF    512
#define EDIM    256
#define BATCH   4096
#define UROWS   131072
#define BM      32         // fused-kernel rows per block

static __device__ __forceinline__ unsigned short f2bf(float x) {
    union { float f; unsigned int i; } c; c.f = x;
    unsigned int u = c.i;
    u += 0x7fffu + ((u >> 16) & 1u);      // round-to-nearest-even
    return (unsigned short)(u >> 16);
}

// ===========================================================================
// FAST PATH
// ws layout: [0,16MiB)        embed4[U][64] u16  (int4x4 per u16; row = 128 B)
//            [+16MiB,+0.5MiB) scales[U] f32      (rowmax/7; L2-resident)
//            [+, +256KiB)     W_bf16[256][512]
// embed4 row r, u16 index l (0..63) packs cols 4l..4l+3 as signed nibbles.
// Dequant: v = scale[r] * q;  q in [-7,7].
// ===========================================================================

#define EMBED_PB   2048                     // blocks for embed section
#define CELL_PB    64                       // blocks for cell section
#define WCONV_PB   8                        // blocks for wconv section
#define ROWS_PW    16                       // rows per wave (embed/cell)

__global__ __launch_bounds__(256) void prep_kernel(
    const int* __restrict__ unique_nodes, const float* __restrict__ table,
    const int* __restrict__ nodes, const float* __restrict__ W,
    unsigned short* __restrict__ embed4, float* __restrict__ scales,
    float* __restrict__ out, unsigned short* __restrict__ Wb)
{
    const int wave = threadIdx.x >> 6;
    const int lane = threadIdx.x & 63;
    const int blk  = blockIdx.x;

    if (blk < EMBED_PB) {
        // int4 per-row symmetric quantization of table[unique_nodes[u]]
        const int u0 = (blk * 4 + wave) * ROWS_PW;
        #pragma unroll 2
        for (int t = 0; t < ROWS_PW; ++t) {
            const int u   = u0 + t;
            const int row = unique_nodes[u];
            const f4 e = *(const f4*)(table + (size_t)row * FDIM + lane * 4);
            // row max |.| over 256 values (64 lanes x 4)
            float m = fmaxf(fmaxf(fabsf(e[0]), fabsf(e[1])),
                            fmaxf(fabsf(e[2]), fabsf(e[3])));
            #pragma unroll
            for (int s = 1; s < 64; s <<= 1)
                m = fmaxf(m, __shfl_xor(m, s));
            m = fmaxf(m, 1e-30f);
            const float inv = 7.0f / m;
            unsigned short pk = 0;
            #pragma unroll
            for (int j = 0; j < 4; ++j) {
                float qf = __builtin_rintf(e[j] * inv);
                qf = fminf(fmaxf(qf, -7.0f), 7.0f);
                const int q = (int)qf;
                pk |= (unsigned short)((q & 0xF) << (4 * j));
            }
            embed4[((size_t)u << 6) + lane] = pk;
            if (lane == 0) scales[u] = m * (1.0f / 7.0f);
        }
    } else if (blk < EMBED_PB + CELL_PB) {
        // out[b][0][:] = table[nodes[b][0]][:]  (exact f32 copy)
        const int b0 = ((blk - EMBED_PB) * 4 + wave) * ROWS_PW;
        #pragma unroll 4
        for (int t = 0; t < ROWS_PW; ++t) {
            const int b = b0 + t;
            const int node = nodes[b * 5];
            const f4 e = *(const f4*)(table + (size_t)node * FDIM + lane * 4);
            *(f4*)(out + (size_t)b * 5 * FDIM + lane * 4) = e;
        }
    } else {
        // Wb = bf16(W): 32768 f4-quads over 8 blocks x 256 threads x 16 iters
        const int base = (blk - EMBED_PB - CELL_PB) * 256 * 16 + threadIdx.x;
        #pragma unroll 4
        for (int t = 0; t < 16; ++t) {
            const int idx = base + t * 256;
            const f4 w = *(const f4*)(W + (size_t)idx * 4);
            u16x4 o;
            #pragma unroll
            for (int j = 0; j < 4; ++j) o[j] = f2bf(w[j]);
            *(u16x4*)(Wb + (size_t)idx * 4) = o;
        }
    }
}

// Fused gather + GEMM + SiLU. Block = 512 threads (8 waves), owns BM=32 rows.
// Phase 1: int4 gather into XOR-swizzled LDS A-tile (bf16, 32 KB).
//   Pair-wise: half-wave per row; per k-iter each lane loads 4 B = 8 int4
//   cols (8*l32..+8) of one embed row (128 B/visit = 1 cache line).
//   Scale is folded into val in the prologue: val_eff = mask_val*scale[col].
// Phase 2: mfma_f32_16x16x32_bf16; A-frags ds_read_b128 from LDS (swizzled,
//   conflict-free), B-frags direct from L2-resident Wb. Wave-tile 32x32.
// Swizzle: byte(r,2k) = r*1024 + ((2k) ^ ((r&7)<<4)); all accesses 16B-aligned.
__global__ __launch_bounds__(512, 4) void fused_kernel(
    const int* __restrict__ mask_col, const float* __restrict__ mask_val,
    const unsigned int* __restrict__ embed4, const float* __restrict__ scales,
    const int* __restrict__ nodes, const float* __restrict__ table,
    const unsigned short* __restrict__ Wb, const float* __restrict__ bias,
    float* __restrict__ out)
{
    __shared__ unsigned short As[BM * TWOF];   // 32 KB, swizzled
    char* const As_b = (char*)As;

    const int wave  = threadIdx.x >> 6;
    const int lane  = threadIdx.x & 63;
    const int half  = lane >> 5;       // 0/1: which row of the pair
    const int l32   = lane & 31;
    const int rbase = blockIdx.x * BM;

    // ---------------- Phase 1: gather (2 pairs = 4 rows per wave) ----------
    #pragma unroll
    for (int p = 0; p < 2; ++p) {
        const int lr = wave * 4 + p * 2;       // local row (pair base)
        const int gi = rbase + lr;             // global row (pair base)

        // lanes 0..31 -> row gi's 32 entries; lanes 32..63 -> row gi+1's
        const int j   = gi * KNEI + lane;
        const int col = mask_col[j];
        const float val = mask_val[j] * scales[col];   // fold dequant scale

        // self row for this half-wave (independent: issue early)
        const int i_g = gi + half;
        const int nfr = nodes[(i_g >> 2) * 5 + 1 + (i_g & 3)];
        const float* sp = table + (size_t)nfr * FDIM + l32 * 8;
        const f4 s0 = *(const f4*)sp;
        const f4 s1 = *(const f4*)(sp + 4);

        f4 accA = (f4){0.f,0.f,0.f,0.f};   // cols 8*l32+0..3
        f4 accB = (f4){0.f,0.f,0.f,0.f};   // cols 8*l32+4..7
        #pragma unroll 8
        for (int k = 0; k < KNEI; ++k) {
            const int   c = __shfl(col, (lane & 32) + k);
            const float v = __shfl(val, (lane & 32) + k);
            const unsigned int w = embed4[((size_t)c << 5) + l32];  // 8 int4
            #pragma unroll
            for (int d = 0; d < 4; ++d) {
                const int qa = ((int)(w << (28 - 4 * d))) >> 28;
                const int qb = ((int)(w << (12 - 4 * d))) >> 28;
                accA[d] += v * (float)qa;
                accB[d] += v * (float)qb;
            }
        }

        const int lrow = lr + half;
        const int swz  = (lrow & 7) << 4;

        // neigh half: cols 8*l32..+8 -> bytes l32*16 (^swz)
        u32x4 on;
        on[0] = (unsigned)f2bf(accA[0]) | ((unsigned)f2bf(accA[1]) << 16);
        on[1] = (unsigned)f2bf(accA[2]) | ((unsigned)f2bf(accA[3]) << 16);
        on[2] = (unsigned)f2bf(accB[0]) | ((unsigned)f2bf(accB[1]) << 16);
        on[3] = (unsigned)f2bf(accB[2]) | ((unsigned)f2bf(accB[3]) << 16);
        *(u32x4*)(As_b + lrow * 1024 + ((l32 * 16) ^ swz)) = on;

        // self half: cols 256+8*l32 -> bytes 512+l32*16 (^swz)
        u32x4 os;
        os[0] = (unsigned)f2bf(s0[0]) | ((unsigned)f2bf(s0[1]) << 16);
        os[1] = (unsigned)f2bf(s0[2]) | ((unsigned)f2bf(s0[3]) << 16);
        os[2] = (unsigned)f2bf(s1[0]) | ((unsigned)f2bf(s1[1]) << 16);
        os[3] = (unsigned)f2bf(s1[2]) | ((unsigned)f2bf(s1[3]) << 16);
        *(u32x4*)(As_b + lrow * 1024 + ((512 + l32 * 16) ^ swz)) = os;
    }

    __syncthreads();

    // ---------------- Phase 2: MFMA (wave-tile 32 x 32) --------------------
    const int n_w    = wave * 32;              // this wave's 32 output cols
    const int lrow16 = lane & 15;
    const int koff   = (lane >> 4) * 8;
    const int aswz   = (lrow16 & 7) << 4;

    f32x4 acc[2][2] = {};
    const unsigned short* wp = Wb + (size_t)(n_w + lrow16) * TWOF + koff;

    #pragma unroll 4
    for (int kb = 0; kb < TWOF; kb += 32) {
        const int kbyte = (koff + kb) * 2;
        const bf16x8 a0 = *(const bf16x8*)(As_b + (lrow16     ) * 1024 + (kbyte ^ aswz));
        const bf16x8 a1 = *(const bf16x8*)(As_b + (lrow16 + 16) * 1024 + (kbyte ^ aswz));
        const bf16x8 b0 = *(const bf16x8*)(wp + kb);
        const bf16x8 b1 = *(const bf16x8*)(wp + 16 * TWOF + kb);
        acc[0][0] = __builtin_amdgcn_mfma_f32_16x16x32_bf16(a0, b0, acc[0][0], 0, 0, 0);
        acc[0][1] = __builtin_amdgcn_mfma_f32_16x16x32_bf16(a0, b1, acc[0][1], 0, 0, 0);
        acc[1][0] = __builtin_amdgcn_mfma_f32_16x16x32_bf16(a1, b0, acc[1][0], 0, 0, 0);
        acc[1][1] = __builtin_amdgcn_mfma_f32_16x16x32_bf16(a1, b1, acc[1][1], 0, 0, 0);
    }

    float bn[2];
    #pragma unroll
    for (int ni = 0; ni < 2; ++ni) bn[ni] = bias[n_w + ni * 16 + lrow16];

    // C/D layout: col = lane&15, row = (lane>>4)*4 + j   [verified rounds 2-6]
    #pragma unroll
    for (int mi = 0; mi < 2; ++mi) {
        #pragma unroll
        for (int ni = 0; ni < 2; ++ni) {
            const int n = n_w + ni * 16 + lrow16;
            #pragma unroll
            for (int j = 0; j < 4; ++j) {
                const int i = rbase + mi * 16 + (lane >> 4) * 4 + j;
                float h = acc[mi][ni][j] + bn[ni];
                h = h / (1.0f + __expf(-h));
                out[((size_t)(i >> 2) * 5 + 1 + (i & 3)) * FDIM + n] = h;
            }
        }
    }
}

// ===========================================================================
// FALLBACK PATH (all-f32) — used only if ws_size is too small
// ===========================================================================
__global__ __launch_bounds__(256) void neigh_f32_kernel(
    const int* __restrict__ mask_col, const float* __restrict__ mask_val,
    const int* __restrict__ unique_nodes, const float* __restrict__ table,
    float* __restrict__ neigh)
{
    const int wave = threadIdx.x >> 6;
    const int lane = threadIdx.x & 63;
    const int i = blockIdx.x * 4 + wave;
    int   row_l = 0;
    float val_l = 0.0f;
    if (lane < KNEI) {
        const int j = i * KNEI + lane;
        const int c = mask_col[j];
        val_l = mask_val[j];
        row_l = unique_nodes[c];
    }
    f4 acc = (f4){0.f, 0.f, 0.f, 0.f};
    #pragma unroll 8
    for (int k = 0; k < KNEI; ++k) {
        const int   row = __shfl(row_l, k);
        const float v   = __shfl(val_l, k);
        const f4 e = *(const f4*)(table + (size_t)row * FDIM + lane * 4);
        acc += v * e;
    }
    *(f4*)(neigh + (size_t)i * FDIM + lane * 4) = acc;
}

__global__ __launch_bounds__(256) void cell_kernel(
    const int* __restrict__ nodes, const float* __restrict__ table,
    float* __restrict__ out)
{
    const int wave = threadIdx.x >> 6;
    const int lane = threadIdx.x & 63;
    const int b = blockIdx.x * 4 + wave;
    const int node = nodes[b * 5];
    const f4 e = *(const f4*)(table + (size_t)node * FDIM + lane * 4);
    *(f4*)(out + (size_t)b * 5 * FDIM + lane * 4) = e;
}

__global__ __launch_bounds__(256) void gemm_f32_kernel(
    const float* __restrict__ neigh, const float* __restrict__ table,
    const int* __restrict__ nodes, const float* __restrict__ W,
    const float* __restrict__ bias, float* __restrict__ out)
{
    __shared__ float Asf[16][64];
    __shared__ float Wsf[16][64];
    const int t  = threadIdx.x;
    const int i0 = blockIdx.x * 64;
    const int e0 = blockIdx.y * 64;
    const int r  = t >> 2;
    const int k4 = (t & 3) << 2;
    const int irow = i0 + r;
    const int nfr = nodes[(irow >> 2) * 5 + 1 + (irow & 3)];
    const int tm = (t >> 4) << 2;
    const int tn = (t & 15) << 2;
    float acc[4][4] = {};
    for (int kb = 0; kb < TWOF; kb += 16) {
        const float* asrc = (kb < FDIM)
            ? (neigh + (size_t)irow * FDIM + kb + k4)
            : (table + (size_t)nfr  * FDIM + (kb - FDIM) + k4);
        const f4 av = *(const f4*)asrc;
        const f4 wv = *(const f4*)(W + (size_t)(e0 + r) * TWOF + kb + k4);
        __syncthreads();
        #pragma unroll
        for (int j = 0; j < 4; ++j) { Asf[k4 + j][r] = av[j]; Wsf[k4 + j][r] = wv[j]; }
        __syncthreads();
        #pragma unroll
        for (int k = 0; k < 16; ++k) {
            const f4 a = *(const f4*)&Asf[k][tm];
            const f4 w = *(const f4*)&Wsf[k][tn];
            #pragma unroll
            for (int mi = 0; mi < 4; ++mi)
                #pragma unroll
                for (int ni = 0; ni < 4; ++ni)
                    acc[mi][ni] += a[mi] * w[ni];
        }
    }
    #pragma unroll
    for (int mi = 0; mi < 4; ++mi) {
        const int i  = i0 + tm + mi;
        float* op = out + ((size_t)(i >> 2) * 5 + 1 + (i & 3)) * FDIM + e0 + tn;
        f4 hv;
        #pragma unroll
        for (int ni = 0; ni < 4; ++ni) {
            const float h = acc[mi][ni] + bias[e0 + tn + ni];
            hv[ni] = h / (1.0f + __expf(-h));
        }
        *(f4*)op = hv;
    }
}

// ===========================================================================
extern "C" void kernel_launch(void* const* d_in, const int* in_sizes, int n_in,
                              void* d_out, int out_size, void* d_ws, size_t ws_size,
                              hipStream_t stream)
{
    const int*   nodes        = (const int*)  d_in[0];
    const int*   mask_col     = (const int*)  d_in[2];
    const float* mask_val     = (const float*)d_in[3];
    const int*   unique_nodes = (const int*)  d_in[4];
    const float* table        = (const float*)d_in[5];
    const float* W            = (const float*)d_in[6];
    const float* bias         = (const float*)d_in[7];
    float*       out          = (float*)d_out;

    const size_t EMBED4_B = (size_t)UROWS * 128;              // 16 MiB int4 rows
    const size_t SC_B     = (size_t)UROWS * 4;                // 0.5 MiB scales
    const size_t W_B      = (size_t)EDIM  * TWOF * 2;         // 256 KiB

    if (ws_size >= EMBED4_B + SC_B + W_B) {
        unsigned short* embed4 = (unsigned short*)d_ws;
        float*          scales = (float*)((char*)d_ws + EMBED4_B);
        unsigned short* Wb     = (unsigned short*)((char*)d_ws + EMBED4_B + SC_B);

        prep_kernel<<<EMBED_PB + CELL_PB + WCONV_PB, 256, 0, stream>>>(
            unique_nodes, table, nodes, W, embed4, scales, out, Wb);
        fused_kernel<<<NROWS / BM, 512, 0, stream>>>(
            mask_col, mask_val, (const unsigned int*)embed4, scales,
            nodes, table, Wb, bias, out);
    } else {
        float* neigh = (float*)d_ws;   // 16 MB
        neigh_f32_kernel<<<NROWS / 4, 256, 0, stream>>>(mask_col, mask_val,
                                                        unique_nodes, table, neigh);
        cell_kernel     <<<BATCH / 4, 256, 0, stream>>>(nodes, table, out);
        gemm_f32_kernel <<<dim3(NROWS / 64, EDIM / 64), 256, 0, stream>>>(
            neigh, table, nodes, W, bias, out);
    }
}